// Round 8
// baseline (139.668 us; speedup 1.0000x reference)
//
#include <hip/hip_runtime.h>

// Multihead self-attention with 3-scale relative positional embeddings.
// B=4, S=1024, D=512, H=8, HD=64.  Outputs: out (4,1024,512) f32, attn (4,8,1024,1024) f32.
//
// Skew algebra (verified round 1):
//   Srel_q[i,j]  = q[i] . Er_q[1023 + j - i]
//   Srel_b[i,j]  = q[i] . Er_b[255 + (j>>2) - (i>>2)]
//   Srel_r[i,j]  = q[i] . Er_r[63  + (j>>4) - (i>>4)]
//
// Round-8: lgkm-only barriers (attn-store drain no longer serialized by
// __syncthreads' vmcnt(0); stores float across strips), 3-deep pipelined
// Er loads in buildT, raw v_exp_f32, early p-death via mid-strip attn store.

typedef float f32x4 __attribute__((ext_vector_type(4)));
typedef short s16x8 __attribute__((ext_vector_type(8)));
typedef short s16x4 __attribute__((ext_vector_type(4)));
typedef __bf16 bf16x8 __attribute__((ext_vector_type(8)));

static __device__ __forceinline__ short f2bf(float f) {
    return __builtin_bit_cast(short, (__bf16)f);
}
static __device__ __forceinline__ float bf2f(short s) {
    union { unsigned u; float f; } v;
    v.u = ((unsigned)(unsigned short)s) << 16;
    return v.f;
}
static __device__ __forceinline__ f32x4 MM(s16x8 a, s16x8 b, f32x4 c) {
    return __builtin_amdgcn_mfma_f32_16x16x32_bf16(
        __builtin_bit_cast(bf16x8, a), __builtin_bit_cast(bf16x8, b), c, 0, 0, 0);
}
#define KEEP(x) asm volatile("" : "+v"(x))
// Barrier that drains only LDS (lgkmcnt), NOT global stores (vmcnt): global
// writes keep draining in background across strips.
#define BARL() asm volatile("s_waitcnt lgkmcnt(0)\n\ts_barrier" ::: "memory")

// ---------------------------------------------------------------------------
// K0: one-shot f32 -> bf16 conversion of all reused operands.
// ---------------------------------------------------------------------------
struct CvtArgs {
    const float* src[9];
    short* dst[9];
    unsigned n[9];
};

__global__ __launch_bounds__(256) void convert_kernel(CvtArgs a) {
    const int ai = blockIdx.y;
    const unsigned n = a.n[ai];
    const float* __restrict__ s = a.src[ai];
    short* __restrict__ d = a.dst[ai];
    const unsigned stride = gridDim.x * 256 * 8;
    for (unsigned base = (blockIdx.x * 256 + threadIdx.x) * 8; base < n; base += stride) {
        f32x4 v0 = *(const f32x4*)(s + base);
        f32x4 v1 = *(const f32x4*)(s + base + 4);
        s16x8 o;
        o[0] = f2bf(v0[0]); o[1] = f2bf(v0[1]); o[2] = f2bf(v0[2]); o[3] = f2bf(v0[3]);
        o[4] = f2bf(v1[0]); o[5] = f2bf(v1[1]); o[6] = f2bf(v1[2]); o[7] = f2bf(v1[3]);
        *(s16x8*)(d + base) = o;
    }
}

// ---------------------------------------------------------------------------
// K1: QKV projections, 64x64 wave tiles, swapped operands so all stores are
// vector b64.  768 blocks x 128 thr (2 waves).
// ---------------------------------------------------------------------------
__global__ __launch_bounds__(128, 2) void proj_kernel(
    const short* __restrict__ queryb, const short* __restrict__ keyb, const short* __restrict__ valueb,
    const short* __restrict__ Wqb, const float* __restrict__ bq,
    const short* __restrict__ Wkb, const float* __restrict__ bk,
    const short* __restrict__ Wvb, const float* __restrict__ bv,
    short* __restrict__ qb, short* __restrict__ kb, short* __restrict__ vT)
{
    const int tid = threadIdx.x;
    const int wid = tid >> 6, lane = tid & 63;
    const int l15 = lane & 15, grp = lane >> 4;
    const int gid = blockIdx.x * 2 + wid;     // 0..1535
    const int z = gid >> 9;                   // 0,1,2
    const int r = gid & 511;

    const short *Am, *Bm;
    const float* bias;
    int a0, b0;
    if (z == 0)      { Am = Wqb;    Bm = queryb; bias = bq; a0 = (r >> 6) * 64; b0 = (r & 63) * 64; }
    else if (z == 1) { Am = Wkb;    Bm = keyb;   bias = bk; a0 = (r >> 6) * 64; b0 = (r & 63) * 64; }
    else             { Am = valueb; Bm = Wvb;    bias = bv; a0 = (r >> 3) * 64; b0 = (r & 7) * 64; }

    f32x4 acc[4][4];
    #pragma unroll
    for (int i = 0; i < 4; ++i)
        #pragma unroll
        for (int j = 0; j < 4; ++j)
            acc[i][j] = f32x4{0.f, 0.f, 0.f, 0.f};

    const short* arow0 = Am + (size_t)(a0 + l15) * 512 + grp * 8;
    const short* brow0 = Bm + (size_t)(b0 + l15) * 512 + grp * 8;

    s16x8 aA[4], bA[4], aB[4], bB[4];
    #pragma unroll
    for (int i = 0; i < 4; ++i) {
        aA[i] = *(const s16x8*)(arow0 + (size_t)i * 16 * 512);
        bA[i] = *(const s16x8*)(brow0 + (size_t)i * 16 * 512);
    }
    for (int kk = 0; kk < 512; kk += 32) {
        const int kn = kk + 32;
        if (kn < 512) {
            #pragma unroll
            for (int i = 0; i < 4; ++i) {
                aB[i] = *(const s16x8*)(arow0 + (size_t)i * 16 * 512 + kn);
                bB[i] = *(const s16x8*)(brow0 + (size_t)i * 16 * 512 + kn);
            }
        }
        #pragma unroll
        for (int i = 0; i < 4; ++i)
            #pragma unroll
            for (int j = 0; j < 4; ++j)
                acc[i][j] = MM(aA[i], bA[j], acc[i][j]);
        #pragma unroll
        for (int i = 0; i < 4; ++i) { aA[i] = aB[i]; bA[i] = bB[i]; }
    }

    if (z < 2) {
        short* dst = (z == 0) ? qb : kb;
        #pragma unroll
        for (int i = 0; i < 4; ++i) {
            const int f0 = a0 + i * 16 + grp * 4;
            const f32x4 bv4 = *(const f32x4*)&bias[f0];
            const int h = f0 >> 6, d0 = f0 & 63;
            #pragma unroll
            for (int j = 0; j < 4; ++j) {
                const int srow = b0 + j * 16 + l15;
                const int bb = srow >> 10, sl = srow & 1023;
                s16x4 o;
                #pragma unroll
                for (int g = 0; g < 4; ++g)
                    o[g] = f2bf(acc[i][j][g] + bv4[g]);
                *(s16x4*)&dst[(size_t)((bb * 8 + h) * 1024 + sl) * 64 + d0] = o;
            }
        }
    } else {
        #pragma unroll
        for (int j = 0; j < 4; ++j) {
            const int n = b0 + j * 16 + l15;
            const float bval = bias[n];
            const int h = n >> 6, d = n & 63;
            #pragma unroll
            for (int i = 0; i < 4; ++i) {
                const int s0 = a0 + i * 16 + grp * 4;
                const int bb = s0 >> 10, sl = s0 & 1023;
                s16x4 o;
                #pragma unroll
                for (int g = 0; g < 4; ++g)
                    o[g] = f2bf(acc[i][j][g] + bval);
                *(s16x4*)&vT[(size_t)((bb * 8 + h) * 64 + d) * 1024 + sl] = o;
            }
        }
    }
}

// ---------------------------------------------------------------------------
// K2: persistent fused relative attention, swapped-operand layout.
// Grid 256 x 512thr; block = (b,h, 128-row chunk), 8 strips of 16 rows.
// Thread (wid,grp,l15) holds P[i=l15][j = wid*128 + t*16 + grp*4 + g].
// PS is wave-private (each wave writes/reads only its own 128 cols) -> no
// barrier guards it; barriers protect only RSUM / PACC / tables.
// LDS 155008B:
//   RQ2 x2 [16][1028] bf16 @ 0 / 32896
//   RB2 x2 [16][260]  bf16 @ 65792 / 74112
//   RR2 x2 [16][68]   bf16 @ 82432 / 84608
//   PS      [16][1028] bf16 @ 86784  (XOR-swizzled cols, unnormalized P)
//   PACC    [8][16][68] f32 @ 119680
//   RSUM x2 [16][8] f32     @ 154496 / 154752
// ---------------------------------------------------------------------------
__global__ __launch_bounds__(512, 2) void attn_kernel(
    const short* __restrict__ Eqb, const short* __restrict__ Ebb, const short* __restrict__ Errb,
    const short* __restrict__ qb, const short* __restrict__ kb, const short* __restrict__ vT,
    float* __restrict__ out, float* __restrict__ attn)
{
    __shared__ __align__(16) char smem[155008];
    short* PS   = (short*)(smem + 86784);
    float* PACC = (float*)(smem + 119680);

    const int tid = threadIdx.x;
    const int wid = tid >> 6, lane = tid & 63;
    const int l15 = lane & 15, grp = lane >> 4;

    // XCD-aware bijective swizzle (256 blocks, %8==0).
    const int orig = blockIdx.x;
    const int bid = (orig & 7) * 32 + (orig >> 3);

    const int bh = bid >> 3;
    const int chunk = bid & 7;
    const int h = bh & 7;
    const int b = bh >> 3;

    const short* EqH = Eqb  + (size_t)h * 2047 * 64;
    const short* EbH = Ebb  + (size_t)h * 511 * 64;
    const short* ErH = Errb + (size_t)h * 127 * 64;
    const short* qbH = qb + (size_t)bh * 1024 * 64;
    const short* kbH = kb + (size_t)bh * 1024 * 64;
    const short* vTH = vT + (size_t)bh * 64 * 1024;

    // ---- table builder: 3-deep pipelined Er loads ----
    auto buildT = [&](int i0s, int bb01, s16x8 q0, s16x8 q1) {
        short* RQ2 = (short*)(smem + bb01 * 32896);
        short* RB2 = (short*)(smem + 65792 + bb01 * 8320);
        short* RR2 = (short*)(smem + 82432 + bb01 * 2176);
        const int qbase = 1008 - i0s;
        {
            auto ldq = [&](int cs, s16x8& e0, s16x8& e1) {
                int erow = qbase + cs * 16 + l15; if (erow > 2046) erow = 2046;
                const short* ep = EqH + (size_t)erow * 64 + grp * 8;
                e0 = *(const s16x8*)ep;
                e1 = *(const s16x8*)(ep + 32);
            };
            s16x8 A0, A1, B0, B1, C0, C1;
            ldq(wid, A0, A1);
            ldq(wid + 8, B0, B1);
            ldq(wid + 16, C0, C1);
            for (int cs = wid; cs < 65; cs += 8) {
                f32x4 a = f32x4{0.f, 0.f, 0.f, 0.f};
                a = MM(q0, A0, a);
                a = MM(q1, A1, a);
                A0 = B0; A1 = B1; B0 = C0; B1 = C1;
                ldq(cs + 24, C0, C1);             // clamped; tail loads unused
                const int c = cs * 16 + l15;
                #pragma unroll
                for (int g = 0; g < 4; ++g) {
                    const int ii = grp * 4 + g;
                    const int j = c - 15 + ii;
                    if (j >= 0 && j < 1024) RQ2[ii * 1028 + j] = f2bf(a[g]);
                }
            }
        }
        const int bbase = 252 - (i0s >> 2);
        {
            auto ldb = [&](int cs, s16x8& e0, s16x8& e1) {
                int erow = bbase + cs * 16 + l15; if (erow > 510) erow = 510;
                const short* ep = EbH + (size_t)erow * 64 + grp * 8;
                e0 = *(const s16x8*)ep;
                e1 = *(const s16x8*)(ep + 32);
            };
            s16x8 A0, A1, B0, B1;
            ldb(wid, A0, A1);
            ldb(wid + 8, B0, B1);
            for (int cs = wid; cs < 17; cs += 8) {
                f32x4 a = f32x4{0.f, 0.f, 0.f, 0.f};
                a = MM(q0, A0, a);
                a = MM(q1, A1, a);
                A0 = B0; A1 = B1;
                ldb(cs + 16, B0, B1);
                const int c = cs * 16 + l15;
                const int jq = c - 3 + grp;
                if (jq >= 0 && jq < 256) {
                    #pragma unroll
                    for (int g = 0; g < 4; ++g)
                        RB2[(grp * 4 + g) * 260 + jq] = f2bf(a[g]);
                }
            }
        }
        const int rbase = 63 - (i0s >> 4);
        if (wid < 4) {
            const int c = wid * 16 + l15;
            const short* ep = ErH + (size_t)(rbase + c) * 64 + grp * 8;
            s16x8 e0 = *(const s16x8*)ep;
            s16x8 e1 = *(const s16x8*)(ep + 32);
            f32x4 a = f32x4{0.f, 0.f, 0.f, 0.f};
            a = MM(q0, e0, a);
            a = MM(q1, e1, a);
            #pragma unroll
            for (int g = 0; g < 4; ++g)
                RR2[(grp * 4 + g) * 68 + c] = f2bf(a[g]);
        }
    };

    // ---- prologue ----
    const int i00 = chunk * 128;
    s16x8 qA0 = *(const s16x8*)(qbH + (size_t)(i00 + l15) * 64 + grp * 8);
    s16x8 qA1 = *(const s16x8*)(qbH + (size_t)(i00 + l15) * 64 + 32 + grp * 8);

    s16x8 kf[8][2];
    #pragma unroll
    for (int t = 0; t < 8; ++t) {
        const short* kp = kbH + (size_t)(wid * 128 + t * 16 + l15) * 64 + grp * 8;
        kf[t][0] = *(const s16x8*)kp;
        kf[t][1] = *(const s16x8*)(kp + 32);
    }
    s16x8 vreg[16];
    #pragma unroll
    for (int dvt = 0; dvt < 4; ++dvt)
        #pragma unroll
        for (int kc = 0; kc < 4; ++kc)
            vreg[dvt * 4 + kc] = *(const s16x8*)(vTH + (size_t)(dvt * 16 + l15) * 1024
                                                 + wid * 128 + kc * 32 + grp * 8);

    buildT(i00, 0, qA0, qA1);
    BARL();

    const float SC = 0.125f * 1.4426950408889634f;   // 1/sqrt(64) * log2(e)
    const int swz = (l15 & 3) << 5;                  // PS col XOR swizzle

    for (int s = 0; s < 8; ++s) {
        #pragma unroll
        for (int t = 0; t < 8; ++t) { KEEP(kf[t][0]); KEEP(kf[t][1]); }
        #pragma unroll
        for (int z = 0; z < 16; ++z) KEEP(vreg[z]);

        const int cur = s & 1;
        const int i0 = chunk * 128 + s * 16;
        short* RQ2c = (short*)(smem + cur * 32896);
        short* RB2c = (short*)(smem + 65792 + cur * 8320);
        short* RR2c = (short*)(smem + 82432 + cur * 2176);
        float* RSUMc = (float*)(smem + 154496 + cur * 256);

        // prefetch next strip's q
        s16x8 qn0, qn1;
        if (s < 7) {
            qn0 = *(const s16x8*)(qbH + (size_t)(i0 + 16 + l15) * 64 + grp * 8);
            qn1 = *(const s16x8*)(qbH + (size_t)(i0 + 16 + l15) * 64 + 32 + grp * 8);
        }

        // ---- loop1: QK^T (swapped) + gathers + exp2 -> p (unnormalized) ----
        f32x4 p[8];
        #pragma unroll
        for (int t = 0; t < 8; ++t) {
            f32x4 a = f32x4{0.f, 0.f, 0.f, 0.f};
            a = MM(kf[t][0], qA0, a);
            a = MM(kf[t][1], qA1, a);
            const int jb2 = wid * 128 + t * 16 + grp * 4;
            s16x4 gq4 = *(const s16x4*)&RQ2c[l15 * 1028 + jb2];
            const float rb = bf2f(RB2c[l15 * 260 + wid * 32 + t * 4 + grp]);
            const float rr = bf2f(RR2c[l15 * 68 + wid * 8 + t]);
            const float add = rb + rr;
            f32x4 pe;
            #pragma unroll
            for (int g = 0; g < 4; ++g)
                pe[g] = __builtin_amdgcn_exp2f((a[g] + bf2f(gq4[g]) + add) * SC);
            p[t] = pe;
        }

        // ---- rowsum partial + RSUM (cross-wave) ----
        float part = 0.f;
        #pragma unroll
        for (int t = 0; t < 8; ++t)
            #pragma unroll
            for (int g = 0; g < 4; ++g)
                part += p[t][g];
        part += __shfl_xor(part, 16, 64);
        part += __shfl_xor(part, 32, 64);
        if (lane < 16) RSUMc[lane * 8 + wid] = part;

        // ---- stage unnormalized bf16 P (wave-private, no barrier needed) ----
        #pragma unroll
        for (int t = 0; t < 8; ++t) {
            const int col = (wid * 128 + t * 16 + grp * 4) ^ swz;
            s16x4 o;
            #pragma unroll
            for (int g = 0; g < 4; ++g) o[g] = f2bf(p[t][g]);
            *(s16x4*)&PS[l15 * 1028 + col] = o;
        }
        BARL();                                    // BAR1: RSUM visible (lgkm only)

        // ---- rinv for this thread's row ----
        float rinv;
        {
            f32x4 s0 = *(const f32x4*)&RSUMc[l15 * 8];
            f32x4 s1 = *(const f32x4*)&RSUMc[l15 * 8 + 4];
            rinv = 1.0f / (s0[0] + s0[1] + s0[2] + s0[3] + s1[0] + s1[1] + s1[2] + s1[3]);
        }

        // ---- build next strip's tables (pipelined Er loads) ----
        if (s < 7) buildT(i0 + 16, cur ^ 1, qn0, qn1);

        // ---- attn store from regs (stores float across strips; p dies here) ----
        {
            float* arow = attn + (size_t)(bh * 1024 + i0 + l15) * 1024;
            #pragma unroll
            for (int t = 0; t < 8; ++t) {
                f32x4 o = p[t] * rinv;
                *(f32x4*)&arow[wid * 128 + t * 16 + grp * 4] = o;
            }
        }

        // ---- PV from own-wave PS + register V ----
        const int kh = wid & 1;  (void)kh;
        f32x4 acc[4];
        #pragma unroll
        for (int dvt = 0; dvt < 4; ++dvt) acc[dvt] = f32x4{0.f, 0.f, 0.f, 0.f};
        #pragma unroll
        for (int kc = 0; kc < 4; ++kc) {
            const int col = (wid * 128 + kc * 32 + grp * 8) ^ swz;
            s16x8 bfrag = *(const s16x8*)&PS[l15 * 1028 + col];
            #pragma unroll
            for (int dvt = 0; dvt < 4; ++dvt)
                acc[dvt] = MM(vreg[dvt * 4 + kc], bfrag, acc[dvt]);
        }
        #pragma unroll
        for (int dvt = 0; dvt < 4; ++dvt)
            *(f32x4*)&PACC[(wid * 16 + l15) * 68 + dvt * 16 + grp * 4] = acc[dvt];
        BARL();                                    // BAR2: PACC + tables visible

        // ---- out-reduce ----
        if (tid < 256) {
            const int i = tid >> 4, dvq = tid & 15;
            f32x4 o = f32x4{0.f, 0.f, 0.f, 0.f};
            #pragma unroll
            for (int w = 0; w < 8; ++w)
                o += *(const f32x4*)&PACC[(w * 16 + i) * 68 + dvq * 4];
            f32x4 s0 = *(const f32x4*)&RSUMc[i * 8];
            f32x4 s1 = *(const f32x4*)&RSUMc[i * 8 + 4];
            const float ri = 1.0f / (s0[0] + s0[1] + s0[2] + s0[3] + s1[0] + s1[1] + s1[2] + s1[3]);
            o *= ri;
            *(f32x4*)&out[(size_t)(b * 1024 + i0 + i) * 512 + h * 64 + dvq * 4] = o;
        }

        if (s < 7) { qA0 = qn0; qA1 = qn1; }
    }
}

// ---------------------------------------------------------------------------
extern "C" void kernel_launch(void* const* d_in, const int* in_sizes, int n_in,
                              void* d_out, int out_size, void* d_ws, size_t ws_size,
                              hipStream_t stream)
{
    const float* query = (const float*)d_in[0];
    const float* key   = (const float*)d_in[1];
    const float* value = (const float*)d_in[2];
    const float* Wq = (const float*)d_in[3];
    const float* bq = (const float*)d_in[4];
    const float* Wk = (const float*)d_in[5];
    const float* bk = (const float*)d_in[6];
    const float* Wv = (const float*)d_in[7];
    const float* bv = (const float*)d_in[8];
    const float* Eq = (const float*)d_in[9];
    const float* Eb = (const float*)d_in[10];
    const float* Er = (const float*)d_in[11];

    float* out  = (float*)d_out;
    float* attn = out + (size_t)4 * 1024 * 512;

    short* qb     = (short*)d_ws;
    short* kb     = qb     + 2097152;
    short* vT     = kb     + 2097152;
    short* queryb = vT     + 2097152;
    short* keyb   = queryb + 2097152;
    short* valueb = keyb   + 2097152;
    short* Wqb    = valueb + 2097152;
    short* Wkb    = Wqb    + 262144;
    short* Wvb    = Wkb    + 262144;
    short* Eqb    = Wvb    + 262144;
    short* Ebb    = Eqb    + 1048064;   // 8*2047*64
    short* Errb   = Ebb    + 261632;    // 8*511*64

    CvtArgs a;
    a.src[0] = query; a.dst[0] = queryb; a.n[0] = 2097152;
    a.src[1] = key;   a.dst[1] = keyb;   a.n[1] = 2097152;
    a.src[2] = value; a.dst[2] = valueb; a.n[2] = 2097152;
    a.src[3] = Wq;    a.dst[3] = Wqb;    a.n[3] = 262144;
    a.src[4] = Wk;    a.dst[4] = Wkb;    a.n[4] = 262144;
    a.src[5] = Wv;    a.dst[5] = Wvb;    a.n[5] = 262144;
    a.src[6] = Eq;    a.dst[6] = Eqb;    a.n[6] = 1048064;
    a.src[7] = Eb;    a.dst[7] = Ebb;    a.n[7] = 261632;
    a.src[8] = Er;    a.dst[8] = Errb;   a.n[8] = 65024;

    convert_kernel<<<dim3(64, 9), 256, 0, stream>>>(a);
    proj_kernel<<<768, 128, 0, stream>>>(queryb, keyb, valueb,
                                         Wqb, bq, Wkb, bk, Wvb, bv, qb, kb, vT);
    attn_kernel<<<256, 512, 0, stream>>>(Eqb, Ebb, Errb, qb, kb, vT, out, attn);
}